// Round 6
// baseline (489.047 us; speedup 1.0000x reference)
//
#include <hip/hip_runtime.h>
#include <hip/hip_fp16.h>

#define F_IN 512
#define BKT_BITS 7                 // 128 nodes per bucket
#define NPB (1 << BKT_BITS)
#define NBMAX 1024
#define BWIN 5120                  // fixed bucket window: mean 4096 + 16 sigma
#define EPT 32                     // edges per thread in k_part
#define EPW (256 * EPT)            // 8192 edges per WG

// --- seed per-bucket cursors to window starts ---
__global__ void k_init(int* __restrict__ cursor, int nb) {
    int i = blockIdx.x * blockDim.x + threadIdx.x;
    if (i < nb) cursor[i] = i * BWIN;
}

// --- partition edges into fixed dst-bucket windows, LDS-sorted first.
// Slice is histogrammed, scanned, and bucket-grouped in LDS; the global write
// then emits bucket-runs (~10 words) in ascending order, so a 64-lane store
// touches ~7 cache lines instead of 64. (Transaction-count fix for r5's part.)
__global__ __launch_bounds__(256) void k_part(
    const int* __restrict__ row, const int* __restrict__ col,
    int* __restrict__ cursor, unsigned int* __restrict__ pairs, int E, int nb)
{
    __shared__ unsigned int staged[EPW];        // 32 KB
    __shared__ unsigned short bkt[EPW];         // 16 KB
    __shared__ int hist[NBMAX];                 // 4 KB
    __shared__ int sc[NBMAX];                   // 4 KB (inclusive scan)
    __shared__ int base[NBMAX];                 // 4 KB  -> 60 KB total
    int tid = threadIdx.x;
    int e0 = blockIdx.x * EPW;
    for (int i = tid; i < nb; i += 256) hist[i] = 0;
    __syncthreads();

    int4 c4[EPT / 4];
    int rank[EPT];
    #pragma unroll
    for (int k = 0; k < EPT / 4; ++k) {
        int e = e0 + (tid + k * 256) * 4;
        if (e + 3 < E) {
            c4[k] = ((const int4*)col)[e >> 2];
        } else {
            c4[k].x = (e     < E) ? col[e]     : -1;
            c4[k].y = (e + 1 < E) ? col[e + 1] : -1;
            c4[k].z = (e + 2 < E) ? col[e + 2] : -1;
            c4[k].w = (e + 3 < E) ? col[e + 3] : -1;
        }
        const int* cc = (const int*)&c4[k];
        #pragma unroll
        for (int i = 0; i < 4; ++i)
            rank[4 * k + i] = (cc[i] >= 0) ? atomicAdd(&hist[cc[i] >> BKT_BITS], 1) : 0;
    }
    __syncthreads();

    // bulk global reservation per bucket + seed scan array
    for (int i = tid; i < NBMAX; i += 256) {
        int h = (i < nb) ? hist[i] : 0;
        base[i] = h ? atomicAdd(&cursor[i], h) : 0;
        sc[i] = h;
    }
    __syncthreads();
    // inclusive Hillis-Steele scan over 1024 entries, 4 per thread
    for (int off = 1; off < NBMAX; off <<= 1) {
        int t0 = (tid       >= off) ? sc[tid       - off] : 0;
        int t1 = (tid + 256 >= off) ? sc[tid + 256 - off] : 0;
        int t2 = (tid + 512 >= off) ? sc[tid + 512 - off] : 0;
        int t3 = (tid + 768 >= off) ? sc[tid + 768 - off] : 0;
        __syncthreads();
        sc[tid] += t0; sc[tid + 256] += t1; sc[tid + 512] += t2; sc[tid + 768] += t3;
        __syncthreads();
    }

    // stage: group this WG's edges by bucket in LDS
    #pragma unroll
    for (int k = 0; k < EPT / 4; ++k) {
        int e = e0 + (tid + k * 256) * 4;
        int4 r4;
        if (e + 3 < E) {
            r4 = ((const int4*)row)[e >> 2];
        } else {
            r4.x = (e     < E) ? row[e]     : 0;
            r4.y = (e + 1 < E) ? row[e + 1] : 0;
            r4.z = (e + 2 < E) ? row[e + 2] : 0;
            r4.w = (e + 3 < E) ? row[e + 3] : 0;
        }
        const int* cc = (const int*)&c4[k];
        const int* rr = (const int*)&r4;
        #pragma unroll
        for (int i = 0; i < 4; ++i) {
            if (e + i >= E || cc[i] < 0) continue;
            int b = cc[i] >> BKT_BITS;
            int pos = (sc[b] - hist[b]) + rank[4 * k + i];   // local exclusive + rank
            staged[pos] = ((unsigned int)rr[i] << BKT_BITS)
                        | (unsigned int)(cc[i] & (NPB - 1));
            bkt[pos] = (unsigned short)b;
        }
    }
    __syncthreads();

    // run-grouped write-out
    int vcnt = sc[nb - 1];
    for (int i = tid; i < vcnt; i += 256) {
        int b = bkt[i];
        int gpos = base[b] + (i - (sc[b] - hist[b]));
        if (gpos < (b + 1) * BWIN)                  // overflow guard (never fires)
            pairs[gpos] = staged[i];
    }
}

// --- per-bucket exact CSR: hist+scan, LDS-sorted scatter, then fully
// COALESCED write-back of the sorted src list (no scattered global stores).
__global__ __launch_bounds__(256) void k_csr(
    unsigned int* __restrict__ pairs, const int* __restrict__ cursor,
    int2* __restrict__ pd, float* __restrict__ dinv, int n, int nb)
{
    __shared__ int sorted[BWIN];                    // 20 KB
    __shared__ int hist[NPB];
    __shared__ int sc[NPB];
    __shared__ int curs[NPB];
    int b = blockIdx.x, tid = threadIdx.x;
    int n0 = b << BKT_BITS;
    int w0 = b * BWIN;
    int ec = min(cursor[b] - w0, BWIN);
    if (tid < NPB) hist[tid] = 0;
    __syncthreads();
    // pass 1: histogram (vectorized window read)
    for (int e4 = tid; e4 < BWIN / 4; e4 += 256) {
        uint4 p4 = ((const uint4*)(pairs + w0))[e4];
        int e = e4 * 4;
        const unsigned int* pp = (const unsigned int*)&p4;
        #pragma unroll
        for (int i = 0; i < 4; ++i)
            if (e + i < ec) atomicAdd(&hist[pp[i] & (NPB - 1)], 1);
    }
    __syncthreads();
    if (tid < NPB) sc[tid] = hist[tid];
    __syncthreads();
    for (int off = 1; off < NPB; off <<= 1) {
        int t = (tid < NPB && tid >= off) ? sc[tid - off] : 0;
        __syncthreads();
        if (tid < NPB) sc[tid] += t;
        __syncthreads();
    }
    if (tid < NPB) {
        int st = sc[tid] - hist[tid];               // exclusive start (local)
        curs[tid] = st;
        int node = n0 + tid;
        if (node < n) {
            pd[node] = make_int2(w0 + st, hist[tid]);
            dinv[node] = rsqrtf((float)(hist[tid] + 1));   // +1 self-loop
        }
    }
    __syncthreads();
    // pass 2: re-read window, scatter into LDS (cheap), not global
    for (int e4 = tid; e4 < BWIN / 4; e4 += 256) {
        uint4 p4 = ((const uint4*)(pairs + w0))[e4];
        int e = e4 * 4;
        const unsigned int* pp = (const unsigned int*)&p4;
        #pragma unroll
        for (int i = 0; i < 4; ++i) {
            if (e + i < ec) {
                unsigned int p = pp[i];
                int pos = atomicAdd(&curs[p & (NPB - 1)], 1);
                sorted[pos] = (int)(p >> BKT_BITS);
            }
        }
    }
    __syncthreads();
    // coalesced write-back
    for (int i = tid; i < ec; i += 256)
        ((int*)pairs)[w0 + i] = sorted[i];
}

// --- hs = (x @ W1) * dinv[node] f16; register double-buffer prefetch ---
__global__ __launch_bounds__(256) void k_gemm1(
    const float* __restrict__ x, const float* __restrict__ W1,
    const float* __restrict__ dinv, __half2* __restrict__ hs, int n)
{
    __shared__ float red[4][64 * 17];
    const int lane = threadIdx.x & 63;
    const int wib  = threadIdx.x >> 6;
    const int wave = blockIdx.x * 4 + wib;
    const int nw   = gridDim.x * 4;
    float* rb = red[wib];

    float w[128];
    #pragma unroll
    for (int i = 0; i < 32; ++i) {
        float4 t = ((const float4*)W1)[lane * 32 + i];
        w[4*i+0] = t.x; w[4*i+1] = t.y; w[4*i+2] = t.z; w[4*i+3] = t.w;
    }
    const int q  = lane >> 4;
    const int jj = lane & 15;

    int node = wave;
    float4 a = {}, b = {};
    float di = 0.f;
    if (node < n) {
        const float4* xr = (const float4*)(x + (size_t)node * F_IN);
        a = xr[lane * 2];
        b = xr[lane * 2 + 1];
        di = dinv[node];
    }
    while (node < n) {
        int nxt = node + nw;
        float4 an = {}, bn = {};
        float dn = 0.f;
        if (nxt < n) {                               // prefetch next node
            const float4* xr = (const float4*)(x + (size_t)nxt * F_IN);
            an = xr[lane * 2];
            bn = xr[lane * 2 + 1];
            dn = dinv[nxt];
        }
        float xs[8] = {a.x, a.y, a.z, a.w, b.x, b.y, b.z, b.w};
        float p[16];
        #pragma unroll
        for (int j = 0; j < 16; ++j) p[j] = 0.f;
        #pragma unroll
        for (int i = 0; i < 8; ++i)
            #pragma unroll
            for (int j = 0; j < 16; ++j)
                p[j] = fmaf(xs[i], w[i * 16 + j], p[j]);

        #pragma unroll
        for (int j = 0; j < 16; ++j) rb[lane * 17 + j] = p[j];
        __asm__ volatile("s_waitcnt lgkmcnt(0)" ::: "memory");
        float s = 0.f;
        #pragma unroll
        for (int i = 0; i < 16; ++i) s += rb[(q * 16 + i) * 17 + jj];
        s += __shfl_down(s, 32);
        s += __shfl_down(s, 16);

        float sv = s * di;
        float sn = __shfl_down(sv, 1);
        if (lane < 16 && (lane & 1) == 0) {
            __half2 hv = __halves2half2(__float2half(sv), __float2half(sn));
            hs[node * 8 + (lane >> 1)] = hv;
        }
        node = nxt; a = an; b = bn; di = dn;
    }
}

// --- gather layer-1 + fused gemm2: WAVE per node (8 dim-pairs x 8 edge-slots).
// Zero divergence waste (loop length = this node's degree), csr reads 256B/wave.
__global__ __launch_bounds__(256) void k_agg1(
    const __half2* __restrict__ hs, const int2* __restrict__ pd,
    const int* __restrict__ csr, const float* __restrict__ dinv,
    const float* __restrict__ b1, const float* __restrict__ W2,
    __half2* __restrict__ hs2, int n)
{
    int t = blockIdx.x * blockDim.x + threadIdx.x;
    int node = t >> 6;
    if (node >= n) return;
    int l = t & 63, d = l & 7, slot = l >> 3;
    int2 p = pd[node];
    float2 sum = make_float2(0.f, 0.f);
    for (int e = 0; e < p.y; e += 8) {
        int s = e + slot;
        bool v = s < p.y;
        int a = v ? csr[p.x + s] : 0;
        float2 h = v ? __half22float2(hs[a * 8 + d]) : make_float2(0.f, 0.f);
        sum.x += h.x; sum.y += h.y;
    }
    // reduce across the 8 edge-slots
    sum.x += __shfl_xor(sum.x, 8);  sum.y += __shfl_xor(sum.y, 8);
    sum.x += __shfl_xor(sum.x, 16); sum.y += __shfl_xor(sum.y, 16);
    sum.x += __shfl_xor(sum.x, 32); sum.y += __shfl_xor(sum.y, 32);
    float2 self = __half22float2(hs[node * 8 + d]);  // self-loop (after reduce!)
    sum.x += self.x; sum.y += self.y;

    float di = dinv[node];
    float2 b1v = ((const float2*)b1)[d];
    float va = fmaxf(fmaf(sum.x, di, b1v.x), 0.f);
    float vb = fmaxf(fmaf(sum.y, di, b1v.y), 0.f);
    float ha = 0.f, hb = 0.f;
    #pragma unroll
    for (int k2 = 0; k2 < 8; ++k2) {
        float oa = __shfl(va, k2, 8);                // v[2*k2]
        float ob = __shfl(vb, k2, 8);                // v[2*k2+1]
        ha = fmaf(oa, W2[(2*k2)   * 16 + 2*d],     ha);
        hb = fmaf(oa, W2[(2*k2)   * 16 + 2*d + 1], hb);
        ha = fmaf(ob, W2[(2*k2+1) * 16 + 2*d],     ha);
        hb = fmaf(ob, W2[(2*k2+1) * 16 + 2*d + 1], hb);
    }
    if (l < 8)
        hs2[node * 8 + d] = __halves2half2(__float2half(ha * di), __float2half(hb * di));
}

// --- gather layer-2 + fused bias + log_softmax: wave per node ---
__global__ __launch_bounds__(256) void k_agg2(
    const __half2* __restrict__ hs2, const int2* __restrict__ pd,
    const int* __restrict__ csr, const float* __restrict__ dinv,
    const float* __restrict__ b2, float2* __restrict__ out, int n)
{
    int t = blockIdx.x * blockDim.x + threadIdx.x;
    int node = t >> 6;
    if (node >= n) return;
    int l = t & 63, d = l & 7, slot = l >> 3;
    int2 p = pd[node];
    float2 sum = make_float2(0.f, 0.f);
    for (int e = 0; e < p.y; e += 8) {
        int s = e + slot;
        bool v = s < p.y;
        int a = v ? csr[p.x + s] : 0;
        float2 h = v ? __half22float2(hs2[a * 8 + d]) : make_float2(0.f, 0.f);
        sum.x += h.x; sum.y += h.y;
    }
    sum.x += __shfl_xor(sum.x, 8);  sum.y += __shfl_xor(sum.y, 8);
    sum.x += __shfl_xor(sum.x, 16); sum.y += __shfl_xor(sum.y, 16);
    sum.x += __shfl_xor(sum.x, 32); sum.y += __shfl_xor(sum.y, 32);
    float2 self = __half22float2(hs2[node * 8 + d]);
    sum.x += self.x; sum.y += self.y;

    float di = dinv[node];
    float2 b2v = ((const float2*)b2)[d];
    float vx = fmaf(sum.x, di, b2v.x);
    float vy = fmaf(sum.y, di, b2v.y);
    float m = fmaxf(vx, vy);
    m = fmaxf(m, __shfl_xor(m, 4));
    m = fmaxf(m, __shfl_xor(m, 2));
    m = fmaxf(m, __shfl_xor(m, 1));
    float s = expf(vx - m) + expf(vy - m);
    s += __shfl_xor(s, 4);
    s += __shfl_xor(s, 2);
    s += __shfl_xor(s, 1);
    float ls = logf(s);
    if (l < 8) out[node * 8 + d] = make_float2(vx - m - ls, vy - m - ls);
}

extern "C" void kernel_launch(void* const* d_in, const int* in_sizes, int n_in,
                              void* d_out, int out_size, void* d_ws, size_t ws_size,
                              hipStream_t stream)
{
    const float* x  = (const float*)d_in[0];
    const int*   ei = (const int*)d_in[1];   // [2, E]: row then col
    const float* W1 = (const float*)d_in[2];
    const float* b1 = (const float*)d_in[3];
    const float* W2 = (const float*)d_in[4];
    const float* b2 = (const float*)d_in[5];
    float* out = (float*)d_out;

    const int n = in_sizes[0] / F_IN;            // 100000
    const int E = in_sizes[1] / 2;               // 3.2M
    const int nb = (n + NPB - 1) >> BKT_BITS;    // 782

    // workspace (~24 MB):
    // dinv (n f32) | pd (n int2) | cursor (1024 i32)
    // | pairs/csr (nb*BWIN u32, in-place) | hs (n*16 f16) | hs2 (n*16 f16)
    char* ws = (char*)d_ws;
    size_t o = 0;
    #define ALIGN512(s) (((s) + 511) & ~(size_t)511)
    float* dinv = (float*)(ws + o);           o += ALIGN512((size_t)n * 4);
    int2*  pd   = (int2*)(ws + o);            o += ALIGN512((size_t)n * 8);
    int*   curs = (int*)(ws + o);             o += ALIGN512((size_t)NBMAX * 4);
    unsigned int* pairs = (unsigned int*)(ws + o);
    o += ALIGN512((size_t)nb * BWIN * 4);
    __half2* hs  = (__half2*)(ws + o);        o += ALIGN512((size_t)n * 16 * 2);
    __half2* hs2 = (__half2*)(ws + o);        o += ALIGN512((size_t)n * 16 * 2);
    #undef ALIGN512

    k_init<<<(nb + 255) / 256, 256, 0, stream>>>(curs, nb);
    k_part<<<(E + EPW - 1) / EPW, 256, 0, stream>>>(ei, ei + E, curs, pairs, E, nb);
    k_csr <<<nb, 256, 0, stream>>>(pairs, curs, pd, dinv, n, nb);

    k_gemm1<<<2048, 256, 0, stream>>>(x, W1, dinv, hs, n);
    k_agg1 <<<(n * 64 + 255) / 256, 256, 0, stream>>>(hs, pd, (const int*)pairs,
                                                      dinv, b1, W2, hs2, n);
    k_agg2 <<<(n * 64 + 255) / 256, 256, 0, stream>>>(hs2, pd, (const int*)pairs,
                                                      dinv, b2, (float2*)out, n);
}

// Round 7
// 434.743 us; speedup vs baseline: 1.1249x; 1.1249x over previous
//
#include <hip/hip_runtime.h>
#include <hip/hip_fp16.h>

#define F_IN 512
#define BKT_BITS 7                 // 128 nodes per bucket
#define NPB (1 << BKT_BITS)
#define NBMAX 1024
#define BWIN 5120                  // fixed bucket window: mean 4096 + 16 sigma
#define EPT 32                     // edges per thread in k_part
#define EPW (256 * EPT)            // 8192 edges per WG

// --- seed per-bucket cursors to window starts ---
__global__ void k_init(int* __restrict__ cursor, int nb) {
    int i = blockIdx.x * blockDim.x + threadIdx.x;
    if (i < nb) cursor[i] = i * BWIN;
}

// --- partition edges into fixed dst-bucket windows, LDS-sorted first.
// Slice is histogrammed, scanned, bucket-grouped in LDS; the global write then
// emits bucket-runs in ascending order, so a 64-lane store touches ~7 cache
// lines instead of 64. Scan = 2-barrier hierarchical (fix of r6's 20-barrier).
__global__ __launch_bounds__(256) void k_part(
    const int* __restrict__ row, const int* __restrict__ col,
    int* __restrict__ cursor, unsigned int* __restrict__ pairs, int E, int nb)
{
    __shared__ unsigned int staged[EPW];        // 32 KB
    __shared__ unsigned short bkt[EPW];         // 16 KB
    __shared__ int hist[NBMAX];                 // 4 KB
    __shared__ int sc[NBMAX];                   // 4 KB (inclusive scan)
    __shared__ int base[NBMAX];                 // 4 KB
    __shared__ int wsum[4];
    int tid = threadIdx.x;
    int lane = tid & 63;
    int e0 = blockIdx.x * EPW;
    for (int i = tid; i < nb; i += 256) hist[i] = 0;
    __syncthreads();

    int4 c4[EPT / 4];
    int rank[EPT];
    #pragma unroll
    for (int k = 0; k < EPT / 4; ++k) {
        int e = e0 + (tid + k * 256) * 4;
        if (e + 3 < E) {
            c4[k] = ((const int4*)col)[e >> 2];
        } else {
            c4[k].x = (e     < E) ? col[e]     : -1;
            c4[k].y = (e + 1 < E) ? col[e + 1] : -1;
            c4[k].z = (e + 2 < E) ? col[e + 2] : -1;
            c4[k].w = (e + 3 < E) ? col[e + 3] : -1;
        }
        const int* cc = (const int*)&c4[k];
        #pragma unroll
        for (int i = 0; i < 4; ++i)
            rank[4 * k + i] = (cc[i] >= 0) ? atomicAdd(&hist[cc[i] >> BKT_BITS], 1) : 0;
    }
    __syncthreads();

    // bulk global reservation per bucket + seed per-thread 4-entry chunk
    int i0 = tid * 4;
    int a0 = 0, a1 = 0, a2 = 0, a3 = 0;
    {
        int h0 = (i0     < nb) ? hist[i0]     : 0;
        int h1 = (i0 + 1 < nb) ? hist[i0 + 1] : 0;
        int h2 = (i0 + 2 < nb) ? hist[i0 + 2] : 0;
        int h3 = (i0 + 3 < nb) ? hist[i0 + 3] : 0;
        base[i0]     = h0 ? atomicAdd(&cursor[i0],     h0) : 0;
        if (i0 + 1 < NBMAX) base[i0 + 1] = h1 ? atomicAdd(&cursor[i0 + 1], h1) : 0;
        if (i0 + 2 < NBMAX) base[i0 + 2] = h2 ? atomicAdd(&cursor[i0 + 2], h2) : 0;
        if (i0 + 3 < NBMAX) base[i0 + 3] = h3 ? atomicAdd(&cursor[i0 + 3], h3) : 0;
        a0 = h0; a1 = h1; a2 = h2; a3 = h3;
    }
    // hierarchical inclusive scan: serial-4 -> wave shfl_up -> 4 wave sums
    int s = a0 + a1 + a2 + a3;
    int ws = s;
    #pragma unroll
    for (int off = 1; off < 64; off <<= 1) {
        int t = __shfl_up(ws, off);
        if (lane >= off) ws += t;
    }
    if (lane == 63) wsum[tid >> 6] = ws;
    __syncthreads();
    int woff = 0;
    #pragma unroll
    for (int k = 0; k < 4; ++k) woff += (k < (tid >> 6)) ? wsum[k] : 0;
    int excl = woff + ws - s;                   // exclusive prefix of entry i0
    sc[i0]     = excl + a0;
    sc[i0 + 1] = excl + a0 + a1;
    sc[i0 + 2] = excl + a0 + a1 + a2;
    sc[i0 + 3] = excl + s;
    __syncthreads();

    // stage: group this WG's edges by bucket in LDS
    #pragma unroll
    for (int k = 0; k < EPT / 4; ++k) {
        int e = e0 + (tid + k * 256) * 4;
        int4 r4;
        if (e + 3 < E) {
            r4 = ((const int4*)row)[e >> 2];
        } else {
            r4.x = (e     < E) ? row[e]     : 0;
            r4.y = (e + 1 < E) ? row[e + 1] : 0;
            r4.z = (e + 2 < E) ? row[e + 2] : 0;
            r4.w = (e + 3 < E) ? row[e + 3] : 0;
        }
        const int* cc = (const int*)&c4[k];
        const int* rr = (const int*)&r4;
        #pragma unroll
        for (int i = 0; i < 4; ++i) {
            if (e + i >= E || cc[i] < 0) continue;
            int b = cc[i] >> BKT_BITS;
            int pos = (sc[b] - hist[b]) + rank[4 * k + i];   // local excl + rank
            staged[pos] = ((unsigned int)rr[i] << BKT_BITS)
                        | (unsigned int)(cc[i] & (NPB - 1));
            bkt[pos] = (unsigned short)b;
        }
    }
    __syncthreads();

    // run-grouped write-out (ascending bucket order -> few lines per store)
    int vcnt = sc[nb - 1];
    for (int i = tid; i < vcnt; i += 256) {
        int b = bkt[i];
        int gpos = base[b] + (i - (sc[b] - hist[b]));
        if (gpos < (b + 1) * BWIN)                  // overflow guard (never fires)
            pairs[gpos] = staged[i];
    }
}

// --- per-bucket exact CSR: hist+scan, LDS-sorted scatter, then fully
// COALESCED write-back of the sorted src list (no scattered global stores).
__global__ __launch_bounds__(256) void k_csr(
    unsigned int* __restrict__ pairs, const int* __restrict__ cursor,
    int2* __restrict__ pd, float* __restrict__ dinv, int n, int nb)
{
    __shared__ int sorted[BWIN];                    // 20 KB
    __shared__ int hist[NPB];
    __shared__ int sc[NPB];
    __shared__ int curs[NPB];
    int b = blockIdx.x, tid = threadIdx.x;
    int n0 = b << BKT_BITS;
    int w0 = b * BWIN;
    int ec = min(cursor[b] - w0, BWIN);
    if (tid < NPB) hist[tid] = 0;
    __syncthreads();
    // pass 1: histogram (vectorized window read)
    for (int e4 = tid; e4 < BWIN / 4; e4 += 256) {
        uint4 p4 = ((const uint4*)(pairs + w0))[e4];
        int e = e4 * 4;
        const unsigned int* pp = (const unsigned int*)&p4;
        #pragma unroll
        for (int i = 0; i < 4; ++i)
            if (e + i < ec) atomicAdd(&hist[pp[i] & (NPB - 1)], 1);
    }
    __syncthreads();
    if (tid < NPB) sc[tid] = hist[tid];
    __syncthreads();
    for (int off = 1; off < NPB; off <<= 1) {
        int t = (tid < NPB && tid >= off) ? sc[tid - off] : 0;
        __syncthreads();
        if (tid < NPB) sc[tid] += t;
        __syncthreads();
    }
    if (tid < NPB) {
        int st = sc[tid] - hist[tid];               // exclusive start (local)
        curs[tid] = st;
        int node = n0 + tid;
        if (node < n) {
            pd[node] = make_int2(w0 + st, hist[tid]);
            dinv[node] = rsqrtf((float)(hist[tid] + 1));   // +1 self-loop
        }
    }
    __syncthreads();
    // pass 2: re-read window, scatter into LDS (cheap), not global
    for (int e4 = tid; e4 < BWIN / 4; e4 += 256) {
        uint4 p4 = ((const uint4*)(pairs + w0))[e4];
        int e = e4 * 4;
        const unsigned int* pp = (const unsigned int*)&p4;
        #pragma unroll
        for (int i = 0; i < 4; ++i) {
            if (e + i < ec) {
                unsigned int p = pp[i];
                int pos = atomicAdd(&curs[p & (NPB - 1)], 1);
                sorted[pos] = (int)(p >> BKT_BITS);
            }
        }
    }
    __syncthreads();
    // coalesced write-back
    for (int i = tid; i < ec; i += 256)
        ((int*)pairs)[w0 + i] = sorted[i];
}

// --- hs = (x @ W1) * dinv[node] f16; register double-buffer prefetch ---
__global__ __launch_bounds__(256) void k_gemm1(
    const float* __restrict__ x, const float* __restrict__ W1,
    const float* __restrict__ dinv, __half2* __restrict__ hs, int n)
{
    __shared__ float red[4][64 * 17];
    const int lane = threadIdx.x & 63;
    const int wib  = threadIdx.x >> 6;
    const int wave = blockIdx.x * 4 + wib;
    const int nw   = gridDim.x * 4;
    float* rb = red[wib];

    float w[128];
    #pragma unroll
    for (int i = 0; i < 32; ++i) {
        float4 t = ((const float4*)W1)[lane * 32 + i];
        w[4*i+0] = t.x; w[4*i+1] = t.y; w[4*i+2] = t.z; w[4*i+3] = t.w;
    }
    const int q  = lane >> 4;
    const int jj = lane & 15;

    int node = wave;
    float4 a = {}, b = {};
    float di = 0.f;
    if (node < n) {
        const float4* xr = (const float4*)(x + (size_t)node * F_IN);
        a = xr[lane * 2];
        b = xr[lane * 2 + 1];
        di = dinv[node];
    }
    while (node < n) {
        int nxt = node + nw;
        float4 an = {}, bn = {};
        float dn = 0.f;
        if (nxt < n) {                               // prefetch next node
            const float4* xr = (const float4*)(x + (size_t)nxt * F_IN);
            an = xr[lane * 2];
            bn = xr[lane * 2 + 1];
            dn = dinv[nxt];
        }
        float xs[8] = {a.x, a.y, a.z, a.w, b.x, b.y, b.z, b.w};
        float p[16];
        #pragma unroll
        for (int j = 0; j < 16; ++j) p[j] = 0.f;
        #pragma unroll
        for (int i = 0; i < 8; ++i)
            #pragma unroll
            for (int j = 0; j < 16; ++j)
                p[j] = fmaf(xs[i], w[i * 16 + j], p[j]);

        #pragma unroll
        for (int j = 0; j < 16; ++j) rb[lane * 17 + j] = p[j];
        __asm__ volatile("s_waitcnt lgkmcnt(0)" ::: "memory");
        float s = 0.f;
        #pragma unroll
        for (int i = 0; i < 16; ++i) s += rb[(q * 16 + i) * 17 + jj];
        s += __shfl_down(s, 32);
        s += __shfl_down(s, 16);

        float sv = s * di;
        float sn = __shfl_down(sv, 1);
        if (lane < 16 && (lane & 1) == 0) {
            __half2 hv = __halves2half2(__float2half(sv), __float2half(sn));
            hs[node * 8 + (lane >> 1)] = hv;
        }
        node = nxt; a = an; b = bn; di = dn;
    }
}

// --- gather layer-1 + fused gemm2: 8 lanes/node, half2 loads (r5-proven) ---
__global__ __launch_bounds__(256) void k_agg1(
    const __half2* __restrict__ hs, const int2* __restrict__ pd,
    const int* __restrict__ csr, const float* __restrict__ dinv,
    const float* __restrict__ b1, const float* __restrict__ W2,
    __half2* __restrict__ hs2, int n)
{
    int t = blockIdx.x * blockDim.x + threadIdx.x;
    int node = t >> 3, j2 = t & 7;                   // lane owns dims {2j2, 2j2+1}
    if (node >= n) return;
    int2 p = pd[node];
    int e = p.x, s1 = p.x + p.y;
    float2 sum = __half22float2(hs[node * 8 + j2]);  // self-loop
    for (; e + 8 <= s1; e += 8) {
        int a0 = csr[e],   a1 = csr[e+1], a2 = csr[e+2], a3 = csr[e+3];
        int a4 = csr[e+4], a5 = csr[e+5], a6 = csr[e+6], a7 = csr[e+7];
        float2 v0 = __half22float2(hs[a0 * 8 + j2]);
        float2 v1 = __half22float2(hs[a1 * 8 + j2]);
        float2 v2 = __half22float2(hs[a2 * 8 + j2]);
        float2 v3 = __half22float2(hs[a3 * 8 + j2]);
        float2 v4 = __half22float2(hs[a4 * 8 + j2]);
        float2 v5 = __half22float2(hs[a5 * 8 + j2]);
        float2 v6 = __half22float2(hs[a6 * 8 + j2]);
        float2 v7 = __half22float2(hs[a7 * 8 + j2]);
        sum.x += ((v0.x+v1.x)+(v2.x+v3.x)) + ((v4.x+v5.x)+(v6.x+v7.x));
        sum.y += ((v0.y+v1.y)+(v2.y+v3.y)) + ((v4.y+v5.y)+(v6.y+v7.y));
    }
    for (; e < s1; ++e) {
        float2 v = __half22float2(hs[csr[e] * 8 + j2]);
        sum.x += v.x; sum.y += v.y;
    }
    float di = dinv[node];
    float2 b1v = ((const float2*)b1)[j2];
    float va = fmaxf(fmaf(sum.x, di, b1v.x), 0.f);
    float vb = fmaxf(fmaf(sum.y, di, b1v.y), 0.f);
    float ha = 0.f, hb = 0.f;
    #pragma unroll
    for (int k2 = 0; k2 < 8; ++k2) {
        float oa = __shfl(va, k2, 8);                // v[2*k2]
        float ob = __shfl(vb, k2, 8);                // v[2*k2+1]
        ha = fmaf(oa, W2[(2*k2)   * 16 + 2*j2],     ha);
        hb = fmaf(oa, W2[(2*k2)   * 16 + 2*j2 + 1], hb);
        ha = fmaf(ob, W2[(2*k2+1) * 16 + 2*j2],     ha);
        hb = fmaf(ob, W2[(2*k2+1) * 16 + 2*j2 + 1], hb);
    }
    hs2[node * 8 + j2] = __halves2half2(__float2half(ha * di), __float2half(hb * di));
}

// --- gather layer-2 + fused bias + log_softmax: 8 lanes/node (r5-proven) ---
__global__ __launch_bounds__(256) void k_agg2(
    const __half2* __restrict__ hs2, const int2* __restrict__ pd,
    const int* __restrict__ csr, const float* __restrict__ dinv,
    const float* __restrict__ b2, float2* __restrict__ out, int n)
{
    int t = blockIdx.x * blockDim.x + threadIdx.x;
    int node = t >> 3, j2 = t & 7;
    if (node >= n) return;
    int2 p = pd[node];
    int e = p.x, s1 = p.x + p.y;
    float2 sum = __half22float2(hs2[node * 8 + j2]); // self-loop
    for (; e + 8 <= s1; e += 8) {
        int a0 = csr[e],   a1 = csr[e+1], a2 = csr[e+2], a3 = csr[e+3];
        int a4 = csr[e+4], a5 = csr[e+5], a6 = csr[e+6], a7 = csr[e+7];
        float2 v0 = __half22float2(hs2[a0 * 8 + j2]);
        float2 v1 = __half22float2(hs2[a1 * 8 + j2]);
        float2 v2 = __half22float2(hs2[a2 * 8 + j2]);
        float2 v3 = __half22float2(hs2[a3 * 8 + j2]);
        float2 v4 = __half22float2(hs2[a4 * 8 + j2]);
        float2 v5 = __half22float2(hs2[a5 * 8 + j2]);
        float2 v6 = __half22float2(hs2[a6 * 8 + j2]);
        float2 v7 = __half22float2(hs2[a7 * 8 + j2]);
        sum.x += ((v0.x+v1.x)+(v2.x+v3.x)) + ((v4.x+v5.x)+(v6.x+v7.x));
        sum.y += ((v0.y+v1.y)+(v2.y+v3.y)) + ((v4.y+v5.y)+(v6.y+v7.y));
    }
    for (; e < s1; ++e) {
        float2 v = __half22float2(hs2[csr[e] * 8 + j2]);
        sum.x += v.x; sum.y += v.y;
    }
    float di = dinv[node];
    float2 b2v = ((const float2*)b2)[j2];
    float vx = fmaf(sum.x, di, b2v.x);
    float vy = fmaf(sum.y, di, b2v.y);
    float m = fmaxf(vx, vy);
    #pragma unroll
    for (int off = 4; off >= 1; off >>= 1) m = fmaxf(m, __shfl_xor(m, off));
    float s = expf(vx - m) + expf(vy - m);
    #pragma unroll
    for (int off = 4; off >= 1; off >>= 1) s += __shfl_xor(s, off);
    float ls = logf(s);
    out[node * 8 + j2] = make_float2(vx - m - ls, vy - m - ls);
}

extern "C" void kernel_launch(void* const* d_in, const int* in_sizes, int n_in,
                              void* d_out, int out_size, void* d_ws, size_t ws_size,
                              hipStream_t stream)
{
    const float* x  = (const float*)d_in[0];
    const int*   ei = (const int*)d_in[1];   // [2, E]: row then col
    const float* W1 = (const float*)d_in[2];
    const float* b1 = (const float*)d_in[3];
    const float* W2 = (const float*)d_in[4];
    const float* b2 = (const float*)d_in[5];
    float* out = (float*)d_out;

    const int n = in_sizes[0] / F_IN;            // 100000
    const int E = in_sizes[1] / 2;               // 3.2M
    const int nb = (n + NPB - 1) >> BKT_BITS;    // 782

    // workspace (~24 MB):
    // dinv (n f32) | pd (n int2) | cursor (1024 i32)
    // | pairs/csr (nb*BWIN u32, in-place) | hs (n*16 f16) | hs2 (n*16 f16)
    char* ws = (char*)d_ws;
    size_t o = 0;
    #define ALIGN512(s) (((s) + 511) & ~(size_t)511)
    float* dinv = (float*)(ws + o);           o += ALIGN512((size_t)n * 4);
    int2*  pd   = (int2*)(ws + o);            o += ALIGN512((size_t)n * 8);
    int*   curs = (int*)(ws + o);             o += ALIGN512((size_t)NBMAX * 4);
    unsigned int* pairs = (unsigned int*)(ws + o);
    o += ALIGN512((size_t)nb * BWIN * 4);
    __half2* hs  = (__half2*)(ws + o);        o += ALIGN512((size_t)n * 16 * 2);
    __half2* hs2 = (__half2*)(ws + o);        o += ALIGN512((size_t)n * 16 * 2);
    #undef ALIGN512

    k_init<<<(nb + 255) / 256, 256, 0, stream>>>(curs, nb);
    k_part<<<(E + EPW - 1) / EPW, 256, 0, stream>>>(ei, ei + E, curs, pairs, E, nb);
    k_csr <<<nb, 256, 0, stream>>>(pairs, curs, pd, dinv, n, nb);

    k_gemm1<<<2048, 256, 0, stream>>>(x, W1, dinv, hs, n);
    k_agg1 <<<(n * 8 + 255) / 256, 256, 0, stream>>>(hs, pd, (const int*)pairs,
                                                     dinv, b1, W2, hs2, n);
    k_agg2 <<<(n * 8 + 255) / 256, 256, 0, stream>>>(hs2, pd, (const int*)pairs,
                                                     dinv, b2, (float2*)out, n);
}